// Round 3
// baseline (651.223 us; speedup 1.0000x reference)
//
#include <hip/hip_runtime.h>

// Problem: B=4, H=32, S=2048, D=128, fp32 sliding-window cache shift.
// new_X[b,h,s,:] = X_cache[b,h,s+1,:] for s<S-1 ; = token_X[b,h,0,:] for s=S-1.
// d_out = concat(new_k, new_v, new_q) flat. Pure HBM-bound streaming copy.

namespace {
constexpr unsigned kB = 4, kH = 32, kS = 2048, kD = 128;
constexpr unsigned kN  = kB * kH * kS * kD;      // 33,554,432 floats per cache
constexpr unsigned kN4 = kN / 4;                 // 8,388,608 float4  (= 1<<23)
constexpr unsigned kChunk4 = kS * kD / 4;        // 65,536 float4 per (b,h) (= 1<<16)
constexpr unsigned kRow4   = kD / 4;             // 32 float4 per row
constexpr int kBlocksPerCache = 683;             // 3*683 = 2049 blocks total
} // namespace

__global__ __launch_bounds__(256) void sliding_cache_shift_kernel(
    const float4* __restrict__ kc, const float4* __restrict__ vc,
    const float4* __restrict__ qc,
    const float4* __restrict__ kt, const float4* __restrict__ vt,
    const float4* __restrict__ qt,
    float4* __restrict__ out) {
  // Block-level cache split: blocks [0,683) -> k, [683,1366) -> v, rest -> q.
  const unsigned cache = blockIdx.x / kBlocksPerCache;          // uniform per block
  const unsigned blk   = blockIdx.x - cache * kBlocksPerCache;  // block idx within cache

  const float4* __restrict__ src = (cache == 0) ? kc : (cache == 1) ? vc : qc;
  const float4* __restrict__ tok = (cache == 0) ? kt : (cache == 1) ? vt : qt;
  float4* __restrict__ dst = out + (size_t)cache * kN4;

  const unsigned stride = kBlocksPerCache * 256u;
  for (unsigned i = blk * 256u + threadIdx.x; i < kN4; i += stride) {
    const unsigned p = i & (kChunk4 - 1u);       // position inside (b,h) chunk
    float4 val;
    if (p < kChunk4 - kRow4) {
      // shifted copy: output row s <- input row s+1 (contiguous, +32 float4)
      val = src[i + kRow4];
    } else {
      // last row of the chunk <- the new token
      const unsigned bh = i >> 16;               // (b,h) chunk index
      val = tok[bh * kRow4 + (p & (kRow4 - 1u))];
    }
    dst[i] = val;
  }
}

extern "C" void kernel_launch(void* const* d_in, const int* in_sizes, int n_in,
                              void* d_out, int out_size, void* d_ws, size_t ws_size,
                              hipStream_t stream) {
  // Inputs in setup_inputs() order:
  // 0: k_cache, 1: v_cache, 2: q_cache, 3: key, 4: value, 5: query (all fp32)
  const float4* kc = (const float4*)d_in[0];
  const float4* vc = (const float4*)d_in[1];
  const float4* qc = (const float4*)d_in[2];
  const float4* kt = (const float4*)d_in[3];
  const float4* vt = (const float4*)d_in[4];
  const float4* qt = (const float4*)d_in[5];
  float4* out = (float4*)d_out;

  const int block = 256;
  const int grid = 3 * kBlocksPerCache;  // 2049 blocks, ~8 per CU
  sliding_cache_shift_kernel<<<grid, block, 0, stream>>>(kc, vc, qc, kt, vt, qt, out);
}